// Round 1
// baseline (1211.195 us; speedup 1.0000x reference)
//
#include <hip/hip_runtime.h>
#include <hip/hip_bf16.h>

// LSTM H=1024, B=256, T=256, C=10 — round 14.
// Round 13 counters: step = 10.5k cyc, ~50% of it LDS-unit serialization,
// dominated by 4x-redundant B-frag reads (all 4 gate-waves read the same
// hstage data: 256 KB/step of 64 KB unique). This round keeps the PROVEN
// round-11/13 sync skeleton byte-identical (flags, det/lcl, staging loads,
// t=0 skip) and restructures ONLY the compute core:
//  - MFMA 16x16x32 -> 32x32x16. Waves = (gate-pair gp, k-quarter kq).
//    One 32-col B-frag read (ds_read_b128) feeds TWO gates' MFMAs:
//    B-reads 256 -> 128 wave-insts/step. A-frags still 128 regs (AGPR).
//  - zb -> [4 kq][4 gate][32 col][32 row] f32 with XOR-swizzled 4-row
//    groups (grp ^ (col&7), same formula on write AND read): b128 both
//    sides (zb 256 b32 -> 128 b128-insts total).
//  - epilogue on 256 threads, 4 rows each (creg[4]); h packed to one
//    8-B store per thread.
//  - frag short idx per bt-slice: (j>>4)*512 + ((j>>3)&1)*256 + nn*8 + (j&7)
//    (32x32x16 B-frag order: col=lane&31, k=(lane>>5)*8+e).
// Predicted: dur 1119 -> ~990-1060 us, bank conflicts stay ~0.

#define H 1024
#define B 256
#define T 256
#define NCLS 10

typedef __attribute__((ext_vector_type(8))) short short8;   // 8 bf16
typedef __attribute__((ext_vector_type(4))) float f32x4;
typedef __attribute__((ext_vector_type(16))) float f32x16;
typedef unsigned long long ull;

__device__ inline unsigned short bf16_bits(float f) {
    union { __hip_bfloat16 h; unsigned short u; } cv;
    cv.h = __float2bfloat16(f);
    return cv.u;
}

#define L2E 1.4426950408889634f
__device__ inline float sigm_fast(float x) {
    float e = __builtin_amdgcn_exp2f(-L2E * x);
    return __builtin_amdgcn_rcpf(1.0f + e);
}
__device__ inline float tanh_fast(float x) {
    float e = __builtin_amdgcn_exp2f((2.0f * L2E) * x);     // e^(2x)
    return 1.0f - 2.0f * __builtin_amdgcn_rcpf(1.0f + e);   // +-sat correct
}

// h frag layout (per 512 KB buffer), 32x32x16 B-frag order, per bt-slice:
//   short index of (j in [0,1024), b-in-slice nn in [0,32)):
//   bt*32768 + (j>>4)*512 + ((j>>3)&1)*256 + nn*8 + (j&7)

__global__ __launch_bounds__(512)
__attribute__((amdgpu_waves_per_eu(2, 2)))
void lstm_persist(
    const float* __restrict__ x,
    const float* __restrict__ Wgh, const float* __restrict__ Wih,
    const float* __restrict__ Wfh, const float* __restrict__ Woh,
    const float* __restrict__ Wgx, const float* __restrict__ Wix,
    const float* __restrict__ Wfx, const float* __restrict__ Wox,
    const float* __restrict__ bg, const float* __restrict__ bi,
    const float* __restrict__ bf_, const float* __restrict__ bo,
    char* __restrict__ frag,            // 2 x 524288 bytes (NOT pre-zeroed)
    unsigned* __restrict__ flags,       // 256 flag lines, 128-B stride (IC)
    unsigned* __restrict__ det,         // 256 slots x 4B (IC), zeroed
    float* __restrict__ hfin)           // H x B fp32
{
    __shared__ __align__(16) char hstage[65536];   // full bt h-slice (64 KB)
    __shared__ __align__(16) float zb[16][32][32]; // [kq*4+g][col][swz rows]
    __shared__ float wxl[4][32];
    __shared__ float bsl[4][32];
    __shared__ int sh_lcl;

    const int tid  = threadIdx.x;
    const int lane = tid & 63;
    const int wave = tid >> 6;          // 0..7
    const int gp   = wave >> 2;         // gate pair: 0 -> {g,i}, 1 -> {f,o}
    const int kq   = wave & 3;          // k-quarter (256 of K=1024)
    const int bt = blockIdx.x & 7;      // work mapping == round 11 (unchanged)
    const int jt = blockIdx.x >> 3;
    const int j0 = jt * 32;
    const int b0 = bt * 32;

    // ---- one-time: publish my physical XCD id to my group's det slot ----
    unsigned xcc;
    __asm__ volatile("s_getreg_b32 %0, hwreg(HW_REG_XCC_ID)" : "=s"(xcc));
    xcc &= 7u;
    if (tid == 0)
        __hip_atomic_store(&det[bt * 32 + jt], xcc + 1u,
                           __ATOMIC_RELAXED, __HIP_MEMORY_SCOPE_AGENT);

    if (tid < 128) {
        int g = tid >> 5, r = tid & 31;
        const float* wx = (g == 0) ? Wgx : (g == 1) ? Wix : (g == 2) ? Wfx : Wox;
        const float* bb = (g == 0) ? bg  : (g == 1) ? bi  : (g == 2) ? bf_ : bo;
        wxl[g][r] = wx[j0 + r];
        bsl[g][r] = bb[b0 + r];
    }

    // ---- one-time: W tiles -> registers, 32x32x16 A-fragment order ----
    // A-frag (assumed, mirrors verified 16x16 family): row = lane&31,
    // k = (lane>>5)*8 + e.  awreg[gg][c] covers kstep kq*16+c.
    const float* Wlo = (gp == 0) ? Wgh : Wfh;
    const float* Whi = (gp == 0) ? Wih : Woh;
    short8 awreg[2][16];
#pragma unroll
    for (int gg = 0; gg < 2; ++gg) {
        const float* Wp = gg ? Whi : Wlo;
        const float* wrow = Wp + (j0 + (lane & 31)) * H
                          + kq * 256 + ((lane >> 5) * 8);
#pragma unroll
        for (int c = 0; c < 16; ++c) {
            const float4 f0 = *(const float4*)(wrow + c * 16);
            const float4 f1 = *(const float4*)(wrow + c * 16 + 4);
            short8 s;
            s[0] = (short)bf16_bits(f0.x); s[1] = (short)bf16_bits(f0.y);
            s[2] = (short)bf16_bits(f0.z); s[3] = (short)bf16_bits(f0.w);
            s[4] = (short)bf16_bits(f1.x); s[5] = (short)bf16_bits(f1.y);
            s[6] = (short)bf16_bits(f1.z); s[7] = (short)bf16_bits(f1.w);
            awreg[gg][c] = s;
        }
    }
#pragma unroll
    for (int gg = 0; gg < 2; ++gg)
#pragma unroll
        for (int c = 0; c < 16; ++c)
            __asm__ volatile("" : "+a"(awreg[gg][c]));

    // ---- one-time: group locality verdict (poll my group's 32 det slots) ----
    if (wave == 0) {
        unsigned v;
        while (true) {
            v = __hip_atomic_load(&det[bt * 32 + (lane & 31)],
                                  __ATOMIC_RELAXED, __HIP_MEMORY_SCOPE_AGENT);
            if (__all((int)(v != 0u))) break;
            __builtin_amdgcn_s_sleep(1);
        }
        int same = __all((int)(v == xcc + 1u));
        if (tid == 0) sh_lcl = same;
    }
    __syncthreads();
    const bool lcl = (sh_lcl != 0);

    float creg[4] = {0.f, 0.f, 0.f, 0.f};
    const int nn = tid & 31;
    const int aa = tid >> 5;            // epilogue threads (tid<256): 0..7

    unsigned* myflag = &flags[blockIdx.x * 32];
    unsigned* pollflag = &flags[(((unsigned)lane & 31) * 8 + bt) * 32];

    for (int t = 0; t < T; ++t) {
        const float xv = x[(b0 + nn) * T + t];

        // ---- wait (round-11 IC protocol, unchanged) ----
        if (wave == 0) {
            const unsigned target = (unsigned)t;
            while (true) {
                unsigned v = __hip_atomic_load(pollflag, __ATOMIC_RELAXED,
                                               __HIP_MEMORY_SCOPE_AGENT);
                if (__all((int)(v >= target))) break;
                __builtin_amdgcn_s_sleep(1);
            }
        }
        __syncthreads();

        f32x16 acc0 = {0.f,0.f,0.f,0.f,0.f,0.f,0.f,0.f,
                       0.f,0.f,0.f,0.f,0.f,0.f,0.f,0.f};
        f32x16 acc1 = acc0;

        if (t > 0) {        // h_0 == 0 -> z == 0: skip staging+MFMA at t=0
            // ---- stage the full 64 KB bt h-slice, wide coalesced loads ----
            {
                const char* gbase = frag + (t & 1) * 524288 + bt * 65536 + tid * 16;
                short8 v0, v1, v2, v3, v4, v5, v6, v7;
                if (lcl) {   // XCD-local: L2 exchange (sc0 = L1 bypass only)
                    __asm__ volatile(
                        "global_load_dwordx4 %0, %8, off sc0\n\t"
                        "global_load_dwordx4 %1, %9, off sc0\n\t"
                        "global_load_dwordx4 %2, %10, off sc0\n\t"
                        "global_load_dwordx4 %3, %11, off sc0\n\t"
                        "global_load_dwordx4 %4, %12, off sc0\n\t"
                        "global_load_dwordx4 %5, %13, off sc0\n\t"
                        "global_load_dwordx4 %6, %14, off sc0\n\t"
                        "global_load_dwordx4 %7, %15, off sc0\n\t"
                        "s_waitcnt vmcnt(0)"
                        : "=&v"(v0), "=&v"(v1), "=&v"(v2), "=&v"(v3),
                          "=&v"(v4), "=&v"(v5), "=&v"(v6), "=&v"(v7)
                        : "v"(gbase),         "v"(gbase + 8192),
                          "v"(gbase + 16384), "v"(gbase + 24576),
                          "v"(gbase + 32768), "v"(gbase + 40960),
                          "v"(gbase + 49152), "v"(gbase + 57344)
                        : "memory");
                } else {     // round-11 IC path (proven)
                    __asm__ volatile(
                        "global_load_dwordx4 %0, %8, off sc0 sc1\n\t"
                        "global_load_dwordx4 %1, %9, off sc0 sc1\n\t"
                        "global_load_dwordx4 %2, %10, off sc0 sc1\n\t"
                        "global_load_dwordx4 %3, %11, off sc0 sc1\n\t"
                        "global_load_dwordx4 %4, %12, off sc0 sc1\n\t"
                        "global_load_dwordx4 %5, %13, off sc0 sc1\n\t"
                        "global_load_dwordx4 %6, %14, off sc0 sc1\n\t"
                        "global_load_dwordx4 %7, %15, off sc0 sc1\n\t"
                        "s_waitcnt vmcnt(0)"
                        : "=&v"(v0), "=&v"(v1), "=&v"(v2), "=&v"(v3),
                          "=&v"(v4), "=&v"(v5), "=&v"(v6), "=&v"(v7)
                        : "v"(gbase),         "v"(gbase + 8192),
                          "v"(gbase + 16384), "v"(gbase + 24576),
                          "v"(gbase + 32768), "v"(gbase + 40960),
                          "v"(gbase + 49152), "v"(gbase + 57344)
                        : "memory");
                }
                short8* dd = (short8*)hstage;
                dd[tid +    0] = v0;  dd[tid +  512] = v1;
                dd[tid + 1024] = v2;  dd[tid + 1536] = v3;
                dd[tid + 2048] = v4;  dd[tid + 2560] = v5;
                dd[tid + 3072] = v6;  dd[tid + 3584] = v7;
            }
            __syncthreads();

            // ---- MFMA: 2 gates x 32 rows x 32 cols x K=256 per wave ----
            // ONE B-frag read per kstep feeds both gates (2x reuse).
#pragma unroll
            for (int c = 0; c < 16; ++c) {
                const int ks = (kq << 4) + c;
                short8 bf = *(const short8*)(hstage + ks * 1024 + lane * 16);
                acc0 = __builtin_amdgcn_mfma_f32_32x32x16_bf16(awreg[0][c], bf, acc0, 0, 0, 0);
                acc1 = __builtin_amdgcn_mfma_f32_32x32x16_bf16(awreg[1][c], bf, acc1, 0, 0, 0);
            }
        }

        // C/D (HW-verified 32x32): col = lane&31,
        // row = (reg&3) + 8*(reg>>2) + 4*(lane>>5) = 4*grp + e, grp=2*rq+hi.
        // zb float idx: ((kq*4+g)<<10) + (col<<5) + ((grp^(col&7))<<2) + e.
        {
            float* zbF = &zb[0][0][0];
            const int col = lane & 31;
            const int hi  = lane >> 5;
            const int g0 = gp * 2, g1 = g0 + 1;
#pragma unroll
            for (int rq = 0; rq < 4; ++rq) {
                const int sw = ((2 * rq + hi) ^ (col & 7)) << 2;
                f32x4 w0, w1;
#pragma unroll
                for (int e = 0; e < 4; ++e) {
                    w0[e] = acc0[rq * 4 + e];
                    w1[e] = acc1[rq * 4 + e];
                }
                *(f32x4*)(zbF + ((kq * 4 + g0) << 10) + (col << 5) + sw) = w0;
                *(f32x4*)(zbF + ((kq * 4 + g1) << 10) + (col << 5) + sw) = w1;
            }
        }
        __syncthreads();

        // ---- elementwise epilogue: 256 threads x 4 rows (b128 zb reads) ----
        if (tid < 256) {
            const int r0 = aa * 4;
            const float* zbF = &zb[0][0][0];
            const int sw = (aa ^ (nn & 7)) << 2;
            f32x4 zs[4];
#pragma unroll
            for (int gi = 0; gi < 4; ++gi) {
                f32x4 s = *(const f32x4*)(zbF + (gi << 10) + (nn << 5) + sw);
#pragma unroll
                for (int kk = 1; kk < 4; ++kk)
                    s += *(const f32x4*)(zbF + (((kk << 2) + gi) << 10) + (nn << 5) + sw);
                zs[gi] = s;
            }
            unsigned short hb[4];
#pragma unroll
            for (int q = 0; q < 4; ++q) {
                const int row = r0 + q;
                float zg = zs[0][q] + wxl[0][row] * xv + bsl[0][nn];
                float zi = zs[1][q] + wxl[1][row] * xv + bsl[1][nn];
                float zf = zs[2][q] + wxl[2][row] * xv + bsl[2][nn];
                float zo = zs[3][q] + wxl[3][row] * xv + bsl[3][nn];
                float g  = tanh_fast(zg);
                float ig = sigm_fast(zi);
                float fg = sigm_fast(zf);
                float og = sigm_fast(zo);
                creg[q] = g * ig + creg[q] * fg;
                float hn = tanh_fast(creg[q]) * og;
                hb[q] = bf16_bits(hn);
                if (t == T - 1) hfin[(j0 + row) * B + (b0 + nn)] = hn;
            }
            // h store: 4 rows (j0+r0 .. j0+r0+3) pack into one 8-B store.
            // shorts idx0..idx0+3 (r0%4==0 -> same octet), byte 2*idx0 % 8 == 0.
            const ull val = (ull)hb[0] | ((ull)hb[1] << 16)
                          | ((ull)hb[2] << 32) | ((ull)hb[3] << 48);
            const int jp = j0 + r0;
            short* fb = (short*)(frag + ((t + 1) & 1) * 524288) + bt * 32768;
            short* fdst = fb + (jp >> 4) * 512 + ((jp >> 3) & 1) * 256
                        + nn * 8 + (jp & 7);
            if (lcl) {
                *(volatile ull*)fdst = val;
            } else {
                __hip_atomic_store((ull*)fdst, val, __ATOMIC_RELAXED,
                                   __HIP_MEMORY_SCOPE_AGENT);
            }
        }

        // ---- arrive (round-11 IC protocol, unchanged): barrier drains every
        // wave's store-acks (L2 or IC), then one IC flag store ----
        __syncthreads();
        if (tid == 0) {
            __asm__ volatile("s_waitcnt vmcnt(0)" ::: "memory");
            __hip_atomic_store(myflag, (unsigned)(t + 1), __ATOMIC_RELAXED,
                               __HIP_MEMORY_SCOPE_AGENT);
        }
    }
}

// ---------------- projection + softmax over batch --------------------------
__global__ __launch_bounds__(256) void lstm_final(
    const float* __restrict__ Wph, const float* __restrict__ hfin,
    const float* __restrict__ bp, float* __restrict__ out)
{
    __shared__ float sh[256];
    __shared__ float shm, shs;
    int c = blockIdx.x;
    int b = threadIdx.x;
    float acc = bp[b];
    const float* wr = Wph + c * H;
    for (int k = 0; k < H; ++k)
        acc += wr[k] * hfin[k * B + b];

    sh[b] = acc;
    __syncthreads();
    for (int s = 128; s > 0; s >>= 1) {
        if (b < s) sh[b] = fmaxf(sh[b], sh[b + s]);
        __syncthreads();
    }
    if (b == 0) shm = sh[0];
    __syncthreads();
    float e = expf(acc - shm);
    sh[b] = e;
    __syncthreads();
    for (int s = 128; s > 0; s >>= 1) {
        if (b < s) sh[b] += sh[b + s];
        __syncthreads();
    }
    if (b == 0) shs = sh[0];
    __syncthreads();
    out[b * NCLS + c] = e / shs;
}

extern "C" void kernel_launch(void* const* d_in, const int* in_sizes, int n_in,
                              void* d_out, int out_size, void* d_ws, size_t ws_size,
                              hipStream_t stream)
{
    const float* x   = (const float*)d_in[0];
    const float* Wgx = (const float*)d_in[1];
    const float* Wgh = (const float*)d_in[2];
    const float* Wix = (const float*)d_in[3];
    const float* Wih = (const float*)d_in[4];
    const float* Wfx = (const float*)d_in[5];
    const float* Wfh = (const float*)d_in[6];
    const float* Wox = (const float*)d_in[7];
    const float* Woh = (const float*)d_in[8];
    const float* Wph = (const float*)d_in[9];
    const float* bg  = (const float*)d_in[10];
    const float* bi  = (const float*)d_in[11];
    const float* bfv = (const float*)d_in[12];
    const float* bo  = (const float*)d_in[13];
    const float* bp  = (const float*)d_in[14];

    char* ws = (char*)d_ws;
    char* frag = ws;                                 // 1 MB (2 x 512 KB)
    unsigned* flags = (unsigned*)(ws + 1048576);     // 32 KB (256 x 128 B)
    unsigned* det   = (unsigned*)(ws + 1081344);     // 4 KB (256 x 4 B)
    float* hfin = (float*)(ws + 1085440);            // 1 MB

    // flags+det zeroed via IC-visible memset; frag needs no init (t=0 skip)
    hipMemsetAsync(flags, 0, 36864, stream);

    lstm_persist<<<256, 512, 0, stream>>>(
        x, Wgh, Wih, Wfh, Woh, Wgx, Wix, Wfx, Wox,
        bg, bi, bfv, bo, frag, flags, det, hfin);

    lstm_final<<<NCLS, 256, 0, stream>>>(Wph, hfin, bp, (float*)d_out);
}

// Round 2
// 1190.362 us; speedup vs baseline: 1.0175x; 1.0175x over previous
//
#include <hip/hip_runtime.h>
#include <hip/hip_bf16.h>

// LSTM H=1024, B=256, T=256, C=10 — round 15.
// Round 14 post-mortem: removing 1.5k cyc of LDS B-reads changed nothing ->
// LDS throughput is NOT the critical path. VALUBusy+MfmaUtil ~33% => ~2/3 of
// each step is latency stall in the serial chain (poll -> barrier -> stage
// 64KB vmcnt(0) -> barrier -> MFMA -> barrier -> epilogue -> barrier -> flag).
// Round 15 attacks the chain, keeping the round-11 flag/det protocol:
//  - frag layout IS the B-frag layout (stage was an identity copy), so MFMA
//    B-operands load DIRECTLY from global (sc0 / sc0sc1 paths preserved) into
//    registers with counted-vmcnt waits interleaving loads and MFMA. The
//    64 KB LDS stage, its vmcnt(0) drain, and 2 of 4 barriers are deleted.
//  - per-wave poll of only the 8 producers of its k-quarter (jt in
//    [8kq,8kq+8)). Stores are gated by the zb barrier whose entry requires
//    the union of all quarters' polls = all 32 peers >= t, so the
//    double-buffer WAR exclusion still holds (same proof shape as round 11).
//  - epilogue back on all 512 threads (2 rows each), zb read as f32x2.
//  - waits tied to consumed regs via "+v" so MFMAs can't hoist above them.

#define H 1024
#define B 256
#define T 256
#define NCLS 10

typedef __attribute__((ext_vector_type(8))) short short8;   // 8 bf16
typedef __attribute__((ext_vector_type(2))) float f32x2;
typedef __attribute__((ext_vector_type(4))) float f32x4;
typedef __attribute__((ext_vector_type(16))) float f32x16;

__device__ inline unsigned short bf16_bits(float f) {
    union { __hip_bfloat16 h; unsigned short u; } cv;
    cv.h = __float2bfloat16(f);
    return cv.u;
}

#define L2E 1.4426950408889634f
__device__ inline float sigm_fast(float x) {
    float e = __builtin_amdgcn_exp2f(-L2E * x);
    return __builtin_amdgcn_rcpf(1.0f + e);
}
__device__ inline float tanh_fast(float x) {
    float e = __builtin_amdgcn_exp2f((2.0f * L2E) * x);     // e^(2x)
    return 1.0f - 2.0f * __builtin_amdgcn_rcpf(1.0f + e);   // +-sat correct
}

// h frag layout (per 512 KB buffer), 32x32x16 B-frag order, per bt-slice:
//   short index of (j in [0,1024), b-in-slice nn in [0,32)):
//   bt*32768 + (j>>4)*512 + ((j>>3)&1)*256 + nn*8 + (j&7)
// Wave kq's quarter = bytes [kq*16384, +16384) of the bt-slice; kstep c at
// byte kq*16384 + c*1024 + lane*16 == the 32x32x16 B-frag for that kstep.

#define LOADS4(d0, d1, d2, d3, PTR, SC)                                   \
    __asm__ volatile(                                                     \
        "global_load_dwordx4 %0, %4, off " SC "\n\t"                      \
        "global_load_dwordx4 %1, %4, off offset:1024 " SC "\n\t"          \
        "global_load_dwordx4 %2, %4, off offset:2048 " SC "\n\t"          \
        "global_load_dwordx4 %3, %4, off offset:3072 " SC                  \
        : "=&v"(d0), "=&v"(d1), "=&v"(d2), "=&v"(d3)                      \
        : "v"(PTR));

#define WAIT4(N, d0, d1, d2, d3)                                          \
    __asm__ volatile("s_waitcnt vmcnt(" N ")"                             \
        : "+v"(d0), "+v"(d1), "+v"(d2), "+v"(d3));

#define MM(c, bb)                                                         \
    acc0 = __builtin_amdgcn_mfma_f32_32x32x16_bf16(awreg[0][c], bb, acc0, 0, 0, 0); \
    acc1 = __builtin_amdgcn_mfma_f32_32x32x16_bf16(awreg[1][c], bb, acc1, 0, 0, 0);

#define GATE_MFMA(SC)                                                     \
    {                                                                     \
        short8 b0, b1, b2, b3, b4, b5, b6, b7;                            \
        short8 b8, b9, b10, b11, b12, b13, b14, b15;                      \
        LOADS4(b0, b1, b2, b3, gb, SC)                                    \
        LOADS4(b4, b5, b6, b7, gb + 4096, SC)                             \
        WAIT4("4", b0, b1, b2, b3)                                        \
        MM(0, b0) MM(1, b1) MM(2, b2) MM(3, b3)                           \
        LOADS4(b8, b9, b10, b11, gb + 8192, SC)                           \
        LOADS4(b12, b13, b14, b15, gb + 12288, SC)                        \
        WAIT4("8", b4, b5, b6, b7)                                        \
        MM(4, b4) MM(5, b5) MM(6, b6) MM(7, b7)                           \
        WAIT4("4", b8, b9, b10, b11)                                      \
        MM(8, b8) MM(9, b9) MM(10, b10) MM(11, b11)                       \
        WAIT4("0", b12, b13, b14, b15)                                    \
        MM(12, b12) MM(13, b13) MM(14, b14) MM(15, b15)                   \
    }

__global__ __launch_bounds__(512)
__attribute__((amdgpu_waves_per_eu(2, 2)))
void lstm_persist(
    const float* __restrict__ x,
    const float* __restrict__ Wgh, const float* __restrict__ Wih,
    const float* __restrict__ Wfh, const float* __restrict__ Woh,
    const float* __restrict__ Wgx, const float* __restrict__ Wix,
    const float* __restrict__ Wfx, const float* __restrict__ Wox,
    const float* __restrict__ bg, const float* __restrict__ bi,
    const float* __restrict__ bf_, const float* __restrict__ bo,
    char* __restrict__ frag,            // 2 x 524288 bytes (NOT pre-zeroed)
    unsigned* __restrict__ flags,       // 256 flag lines, 128-B stride (IC)
    unsigned* __restrict__ det,         // 256 slots x 4B (IC), zeroed
    float* __restrict__ hfin)           // H x B fp32
{
    __shared__ __align__(16) float zb[16][32][32]; // [kq*4+g][col][swz rows]
    __shared__ float wxl[4][32];
    __shared__ float bsl[4][32];
    __shared__ int sh_lcl;

    const int tid  = threadIdx.x;
    const int lane = tid & 63;
    const int wave = tid >> 6;          // 0..7
    const int gp   = wave >> 2;         // gate pair: 0 -> {g,i}, 1 -> {f,o}
    const int kq   = wave & 3;          // k-quarter (256 of K=1024)
    const int bt = blockIdx.x & 7;      // work mapping == round 11 (unchanged)
    const int jt = blockIdx.x >> 3;
    const int j0 = jt * 32;
    const int b0 = bt * 32;

    // ---- one-time: publish my physical XCD id to my group's det slot ----
    unsigned xcc;
    __asm__ volatile("s_getreg_b32 %0, hwreg(HW_REG_XCC_ID)" : "=s"(xcc));
    xcc &= 7u;
    if (tid == 0)
        __hip_atomic_store(&det[bt * 32 + jt], xcc + 1u,
                           __ATOMIC_RELAXED, __HIP_MEMORY_SCOPE_AGENT);

    if (tid < 128) {
        int g = tid >> 5, r = tid & 31;
        const float* wx = (g == 0) ? Wgx : (g == 1) ? Wix : (g == 2) ? Wfx : Wox;
        const float* bb = (g == 0) ? bg  : (g == 1) ? bi  : (g == 2) ? bf_ : bo;
        wxl[g][r] = wx[j0 + r];
        bsl[g][r] = bb[b0 + r];
    }

    // ---- one-time: W tiles -> registers, 32x32x16 A-fragment order ----
    // (verified by round-14 pass): row = lane&31, k = (lane>>5)*8 + e.
    const float* Wlo = (gp == 0) ? Wgh : Wfh;
    const float* Whi = (gp == 0) ? Wih : Woh;
    short8 awreg[2][16];
#pragma unroll
    for (int gg = 0; gg < 2; ++gg) {
        const float* Wp = gg ? Whi : Wlo;
        const float* wrow = Wp + (j0 + (lane & 31)) * H
                          + kq * 256 + ((lane >> 5) * 8);
#pragma unroll
        for (int c = 0; c < 16; ++c) {
            const float4 f0 = *(const float4*)(wrow + c * 16);
            const float4 f1 = *(const float4*)(wrow + c * 16 + 4);
            short8 s;
            s[0] = (short)bf16_bits(f0.x); s[1] = (short)bf16_bits(f0.y);
            s[2] = (short)bf16_bits(f0.z); s[3] = (short)bf16_bits(f0.w);
            s[4] = (short)bf16_bits(f1.x); s[5] = (short)bf16_bits(f1.y);
            s[6] = (short)bf16_bits(f1.z); s[7] = (short)bf16_bits(f1.w);
            awreg[gg][c] = s;
        }
    }
#pragma unroll
    for (int gg = 0; gg < 2; ++gg)
#pragma unroll
        for (int c = 0; c < 16; ++c)
            __asm__ volatile("" : "+a"(awreg[gg][c]));

    // ---- one-time: group locality verdict (poll my group's 32 det slots) ----
    if (wave == 0) {
        unsigned v;
        while (true) {
            v = __hip_atomic_load(&det[bt * 32 + (lane & 31)],
                                  __ATOMIC_RELAXED, __HIP_MEMORY_SCOPE_AGENT);
            if (__all((int)(v != 0u))) break;
            __builtin_amdgcn_s_sleep(1);
        }
        int same = __all((int)(v == xcc + 1u));
        if (tid == 0) sh_lcl = same;
    }
    __syncthreads();
    const bool lcl = (sh_lcl != 0);

    float creg[2] = {0.f, 0.f};
    const int nn = tid & 31;
    const int aa = tid >> 5;            // 0..15: rows 2aa, 2aa+1

    unsigned* myflag = &flags[blockIdx.x * 32];
    // per-wave poll set: only the 8 producers of my k-quarter
    unsigned* pollflag = &flags[(((kq << 3) + (lane & 7)) * 8 + bt) * 32];

    for (int t = 0; t < T; ++t) {
        const float xv = x[(b0 + nn) * T + t];

        f32x16 acc0 = {0.f,0.f,0.f,0.f,0.f,0.f,0.f,0.f,
                       0.f,0.f,0.f,0.f,0.f,0.f,0.f,0.f};
        f32x16 acc1 = acc0;

        if (t > 0) {        // h_0 == 0 -> z == 0: skip poll+loads+MFMA at t=0
            // ---- per-wave wait on my 8 producers (IC protocol values) ----
            {
                const unsigned target = (unsigned)t;
                while (true) {
                    unsigned v = __hip_atomic_load(pollflag, __ATOMIC_RELAXED,
                                                   __HIP_MEMORY_SCOPE_AGENT);
                    if (__all((int)(v >= target))) break;
                    __builtin_amdgcn_s_sleep(1);
                }
            }
            // force xv retired so vmcnt counts below are exact
            __asm__ volatile("" :: "v"(xv));

            // ---- B-frags direct from global, counted-vmcnt MFMA ----
            const char* gb = frag + (t & 1) * 524288 + bt * 65536
                           + (kq << 14) + lane * 16;
            if (lcl) {       // XCD-local exchange: L1 bypass only
                GATE_MFMA("sc0")
            } else {         // cross-XCD: IC path (round-11 semantics)
                GATE_MFMA("sc0 sc1")
            }
        }

        // C/D (HW-verified 32x32): col = lane&31,
        // row = (reg&3) + 8*(reg>>2) + 4*(lane>>5) = 4*grp + e, grp=2*rq+hi.
        // zb float idx: ((kq*4+g)<<10) + (col<<5) + ((grp^(col&7))<<2) + e.
        {
            float* zbF = &zb[0][0][0];
            const int col = lane & 31;
            const int hi  = lane >> 5;
            const int g0 = gp * 2, g1 = g0 + 1;
#pragma unroll
            for (int rq = 0; rq < 4; ++rq) {
                const int sw = ((2 * rq + hi) ^ (col & 7)) << 2;
                f32x4 w0, w1;
#pragma unroll
                for (int e = 0; e < 4; ++e) {
                    w0[e] = acc0[rq * 4 + e];
                    w1[e] = acc1[rq * 4 + e];
                }
                *(f32x4*)(zbF + ((kq * 4 + g0) << 10) + (col << 5) + sw) = w0;
                *(f32x4*)(zbF + ((kq * 4 + g1) << 10) + (col << 5) + sw) = w1;
            }
        }
        __syncthreads();   // all waves' polls done => all 32 peers >= t:
                           // stores below cannot overwrite a peer's live read

        // ---- elementwise epilogue: 512 threads x 2 rows (f32x2 zb reads) ----
        {
            const int grp = aa >> 1, half = aa & 1;  // rows 4grp+2half+{0,1}
            const float* zcol = &zb[0][0][0] + (nn << 5);
            const int fo = ((grp ^ (nn & 7)) << 2) + (half << 1);
            f32x2 zs[4];
#pragma unroll
            for (int gi = 0; gi < 4; ++gi) {
                f32x2 s = *(const f32x2*)(zcol + (gi << 10) + fo);
#pragma unroll
                for (int kk = 1; kk < 4; ++kk)
                    s += *(const f32x2*)(zcol + (((kk << 2) + gi) << 10) + fo);
                zs[gi] = s;
            }
            unsigned short hb[2];
#pragma unroll
            for (int q = 0; q < 2; ++q) {
                const int jl = 2 * aa + q;
                float zg = zs[0][q] + wxl[0][jl] * xv + bsl[0][nn];
                float zi = zs[1][q] + wxl[1][jl] * xv + bsl[1][nn];
                float zf = zs[2][q] + wxl[2][jl] * xv + bsl[2][nn];
                float zo = zs[3][q] + wxl[3][jl] * xv + bsl[3][nn];
                float g  = tanh_fast(zg);
                float ig = sigm_fast(zi);
                float fg = sigm_fast(zf);
                float og = sigm_fast(zo);
                creg[q] = g * ig + creg[q] * fg;
                float hn = tanh_fast(creg[q]) * og;
                hb[q] = bf16_bits(hn);
                if (t == T - 1) hfin[(j0 + jl) * B + (b0 + nn)] = hn;
            }
            // h store: rows j0+2aa, j0+2aa+1 -> one 4-B store (same octet).
            const unsigned val = (unsigned)hb[0] | ((unsigned)hb[1] << 16);
            const int jj = j0 + 2 * aa;
            short* fb = (short*)(frag + ((t + 1) & 1) * 524288) + bt * 32768;
            short* fdst = fb + (jj >> 4) * 512 + ((jj >> 3) & 1) * 256
                        + nn * 8 + (jj & 7);
            if (lcl) {
                *(volatile unsigned*)fdst = val;
            } else {
                __hip_atomic_store((unsigned*)fdst, val, __ATOMIC_RELAXED,
                                   __HIP_MEMORY_SCOPE_AGENT);
            }
        }

        // ---- arrive (round-11 IC protocol): barrier drains every wave's
        // store-acks (each wave waits vmcnt before s_barrier), then one flag --
        __syncthreads();
        if (tid == 0) {
            __asm__ volatile("s_waitcnt vmcnt(0)" ::: "memory");
            __hip_atomic_store(myflag, (unsigned)(t + 1), __ATOMIC_RELAXED,
                               __HIP_MEMORY_SCOPE_AGENT);
        }
    }
}

// ---------------- projection + softmax over batch --------------------------
__global__ __launch_bounds__(256) void lstm_final(
    const float* __restrict__ Wph, const float* __restrict__ hfin,
    const float* __restrict__ bp, float* __restrict__ out)
{
    __shared__ float sh[256];
    __shared__ float shm, shs;
    int c = blockIdx.x;
    int b = threadIdx.x;
    float acc = bp[b];
    const float* wr = Wph + c * H;
    for (int k = 0; k < H; ++k)
        acc += wr[k] * hfin[k * B + b];

    sh[b] = acc;
    __syncthreads();
    for (int s = 128; s > 0; s >>= 1) {
        if (b < s) sh[b] = fmaxf(sh[b], sh[b + s]);
        __syncthreads();
    }
    if (b == 0) shm = sh[0];
    __syncthreads();
    float e = expf(acc - shm);
    sh[b] = e;
    __syncthreads();
    for (int s = 128; s > 0; s >>= 1) {
        if (b < s) sh[b] += sh[b + s];
        __syncthreads();
    }
    if (b == 0) shs = sh[0];
    __syncthreads();
    out[b * NCLS + c] = e / shs;
}

extern "C" void kernel_launch(void* const* d_in, const int* in_sizes, int n_in,
                              void* d_out, int out_size, void* d_ws, size_t ws_size,
                              hipStream_t stream)
{
    const float* x   = (const float*)d_in[0];
    const float* Wgx = (const float*)d_in[1];
    const float* Wgh = (const float*)d_in[2];
    const float* Wix = (const float*)d_in[3];
    const float* Wih = (const float*)d_in[4];
    const float* Wfx = (const float*)d_in[5];
    const float* Wfh = (const float*)d_in[6];
    const float* Wox = (const float*)d_in[7];
    const float* Woh = (const float*)d_in[8];
    const float* Wph = (const float*)d_in[9];
    const float* bg  = (const float*)d_in[10];
    const float* bi  = (const float*)d_in[11];
    const float* bfv = (const float*)d_in[12];
    const float* bo  = (const float*)d_in[13];
    const float* bp  = (const float*)d_in[14];

    char* ws = (char*)d_ws;
    char* frag = ws;                                 // 1 MB (2 x 512 KB)
    unsigned* flags = (unsigned*)(ws + 1048576);     // 32 KB (256 x 128 B)
    unsigned* det   = (unsigned*)(ws + 1081344);     // 4 KB (256 x 4 B)
    float* hfin = (float*)(ws + 1085440);            // 1 MB

    // flags+det zeroed via IC-visible memset; frag needs no init (t=0 skip)
    hipMemsetAsync(flags, 0, 36864, stream);

    lstm_persist<<<256, 512, 0, stream>>>(
        x, Wgh, Wih, Wfh, Woh, Wgx, Wix, Wfx, Wox,
        bg, bi, bfv, bo, frag, flags, det, hfin);

    lstm_final<<<NCLS, 256, 0, stream>>>(Wph, hfin, bp, (float*)d_out);
}

// Round 3
// 1106.715 us; speedup vs baseline: 1.0944x; 1.0756x over previous
//
#include <hip/hip_runtime.h>
#include <hip/hip_bf16.h>

// LSTM H=1024, B=256, T=256, C=10 — round 16.
// Round 15 post-mortem closed the model: WRITE_SIZE=4KB/block-step (8B-min
// transactions x 512 stores) proves the h-exchange writes through to HBM/IC —
// HIP volatile lowers with cache-bypass bits on gfx940+, so the "L2-local"
// store path NEVER engaged. Consumer loads (FETCH=0.5MB/step from HBM) ride
// the IC/HBM path too: 32MB/step through shared IC ~= the unexplained ~6-7k
// cyc/step. Round 16 changes ONE thing: the lcl h-store becomes a genuine
// write-back L2 store (inline asm global_store_dword, NO sc bits). Consumer
// sc0 loads then hit the group's own XCD L2 (~250cy, 4.3TB/s local). Flags /
// det / non-lcl fallback / everything else: byte-identical to round 15.
// Safety: det re-proves same-XCD co-residency each run; each frag address is
// only ever written by one XCD; t=0 skips all frag reads; kernel-end release
// flushes L2 for lstm_final's hfin reads.
// Prediction: lcl true -> dur ~700-850us, WRITE_SIZE <30MB, FETCH <60MB.
// If WRITE_SIZE stays 265MB -> lcl false at runtime -> pivot to det-driven
// dynamic grouping next round.

#define H 1024
#define B 256
#define T 256
#define NCLS 10

typedef __attribute__((ext_vector_type(8))) short short8;   // 8 bf16
typedef __attribute__((ext_vector_type(2))) float f32x2;
typedef __attribute__((ext_vector_type(4))) float f32x4;
typedef __attribute__((ext_vector_type(16))) float f32x16;

__device__ inline unsigned short bf16_bits(float f) {
    union { __hip_bfloat16 h; unsigned short u; } cv;
    cv.h = __float2bfloat16(f);
    return cv.u;
}

#define L2E 1.4426950408889634f
__device__ inline float sigm_fast(float x) {
    float e = __builtin_amdgcn_exp2f(-L2E * x);
    return __builtin_amdgcn_rcpf(1.0f + e);
}
__device__ inline float tanh_fast(float x) {
    float e = __builtin_amdgcn_exp2f((2.0f * L2E) * x);     // e^(2x)
    return 1.0f - 2.0f * __builtin_amdgcn_rcpf(1.0f + e);   // +-sat correct
}

// h frag layout (per 512 KB buffer), 32x32x16 B-frag order, per bt-slice:
//   short index of (j in [0,1024), b-in-slice nn in [0,32)):
//   bt*32768 + (j>>4)*512 + ((j>>3)&1)*256 + nn*8 + (j&7)
// Wave kq's quarter = bytes [kq*16384, +16384) of the bt-slice; kstep c at
// byte kq*16384 + c*1024 + lane*16 == the 32x32x16 B-frag for that kstep.

#define LOADS4(d0, d1, d2, d3, PTR, SC)                                   \
    __asm__ volatile(                                                     \
        "global_load_dwordx4 %0, %4, off " SC "\n\t"                      \
        "global_load_dwordx4 %1, %4, off offset:1024 " SC "\n\t"          \
        "global_load_dwordx4 %2, %4, off offset:2048 " SC "\n\t"          \
        "global_load_dwordx4 %3, %4, off offset:3072 " SC                  \
        : "=&v"(d0), "=&v"(d1), "=&v"(d2), "=&v"(d3)                      \
        : "v"(PTR));

#define WAIT4(N, d0, d1, d2, d3)                                          \
    __asm__ volatile("s_waitcnt vmcnt(" N ")"                             \
        : "+v"(d0), "+v"(d1), "+v"(d2), "+v"(d3));

#define MM(c, bb)                                                         \
    acc0 = __builtin_amdgcn_mfma_f32_32x32x16_bf16(awreg[0][c], bb, acc0, 0, 0, 0); \
    acc1 = __builtin_amdgcn_mfma_f32_32x32x16_bf16(awreg[1][c], bb, acc1, 0, 0, 0);

#define GATE_MFMA(SC)                                                     \
    {                                                                     \
        short8 b0, b1, b2, b3, b4, b5, b6, b7;                            \
        short8 b8, b9, b10, b11, b12, b13, b14, b15;                      \
        LOADS4(b0, b1, b2, b3, gb, SC)                                    \
        LOADS4(b4, b5, b6, b7, gb + 4096, SC)                             \
        WAIT4("4", b0, b1, b2, b3)                                        \
        MM(0, b0) MM(1, b1) MM(2, b2) MM(3, b3)                           \
        LOADS4(b8, b9, b10, b11, gb + 8192, SC)                           \
        LOADS4(b12, b13, b14, b15, gb + 12288, SC)                        \
        WAIT4("8", b4, b5, b6, b7)                                        \
        MM(4, b4) MM(5, b5) MM(6, b6) MM(7, b7)                           \
        WAIT4("4", b8, b9, b10, b11)                                      \
        MM(8, b8) MM(9, b9) MM(10, b10) MM(11, b11)                       \
        WAIT4("0", b12, b13, b14, b15)                                    \
        MM(12, b12) MM(13, b13) MM(14, b14) MM(15, b15)                   \
    }

__global__ __launch_bounds__(512)
__attribute__((amdgpu_waves_per_eu(2, 2)))
void lstm_persist(
    const float* __restrict__ x,
    const float* __restrict__ Wgh, const float* __restrict__ Wih,
    const float* __restrict__ Wfh, const float* __restrict__ Woh,
    const float* __restrict__ Wgx, const float* __restrict__ Wix,
    const float* __restrict__ Wfx, const float* __restrict__ Wox,
    const float* __restrict__ bg, const float* __restrict__ bi,
    const float* __restrict__ bf_, const float* __restrict__ bo,
    char* __restrict__ frag,            // 2 x 524288 bytes (NOT pre-zeroed)
    unsigned* __restrict__ flags,       // 256 flag lines, 128-B stride (IC)
    unsigned* __restrict__ det,         // 256 slots x 4B (IC), zeroed
    float* __restrict__ hfin)           // H x B fp32
{
    __shared__ __align__(16) float zb[16][32][32]; // [kq*4+g][col][swz rows]
    __shared__ float wxl[4][32];
    __shared__ float bsl[4][32];
    __shared__ int sh_lcl;

    const int tid  = threadIdx.x;
    const int lane = tid & 63;
    const int wave = tid >> 6;          // 0..7
    const int gp   = wave >> 2;         // gate pair: 0 -> {g,i}, 1 -> {f,o}
    const int kq   = wave & 3;          // k-quarter (256 of K=1024)
    const int bt = blockIdx.x & 7;      // work mapping == round 11 (unchanged)
    const int jt = blockIdx.x >> 3;
    const int j0 = jt * 32;
    const int b0 = bt * 32;

    // ---- one-time: publish my physical XCD id to my group's det slot ----
    unsigned xcc;
    __asm__ volatile("s_getreg_b32 %0, hwreg(HW_REG_XCC_ID)" : "=s"(xcc));
    xcc &= 7u;
    if (tid == 0)
        __hip_atomic_store(&det[bt * 32 + jt], xcc + 1u,
                           __ATOMIC_RELAXED, __HIP_MEMORY_SCOPE_AGENT);

    if (tid < 128) {
        int g = tid >> 5, r = tid & 31;
        const float* wx = (g == 0) ? Wgx : (g == 1) ? Wix : (g == 2) ? Wfx : Wox;
        const float* bb = (g == 0) ? bg  : (g == 1) ? bi  : (g == 2) ? bf_ : bo;
        wxl[g][r] = wx[j0 + r];
        bsl[g][r] = bb[b0 + r];
    }

    // ---- one-time: W tiles -> registers, 32x32x16 A-fragment order ----
    // (verified by round-14 pass): row = lane&31, k = (lane>>5)*8 + e.
    const float* Wlo = (gp == 0) ? Wgh : Wfh;
    const float* Whi = (gp == 0) ? Wih : Woh;
    short8 awreg[2][16];
#pragma unroll
    for (int gg = 0; gg < 2; ++gg) {
        const float* Wp = gg ? Whi : Wlo;
        const float* wrow = Wp + (j0 + (lane & 31)) * H
                          + kq * 256 + ((lane >> 5) * 8);
#pragma unroll
        for (int c = 0; c < 16; ++c) {
            const float4 f0 = *(const float4*)(wrow + c * 16);
            const float4 f1 = *(const float4*)(wrow + c * 16 + 4);
            short8 s;
            s[0] = (short)bf16_bits(f0.x); s[1] = (short)bf16_bits(f0.y);
            s[2] = (short)bf16_bits(f0.z); s[3] = (short)bf16_bits(f0.w);
            s[4] = (short)bf16_bits(f1.x); s[5] = (short)bf16_bits(f1.y);
            s[6] = (short)bf16_bits(f1.z); s[7] = (short)bf16_bits(f1.w);
            awreg[gg][c] = s;
        }
    }
#pragma unroll
    for (int gg = 0; gg < 2; ++gg)
#pragma unroll
        for (int c = 0; c < 16; ++c)
            __asm__ volatile("" : "+a"(awreg[gg][c]));

    // ---- one-time: group locality verdict (poll my group's 32 det slots) ----
    if (wave == 0) {
        unsigned v;
        while (true) {
            v = __hip_atomic_load(&det[bt * 32 + (lane & 31)],
                                  __ATOMIC_RELAXED, __HIP_MEMORY_SCOPE_AGENT);
            if (__all((int)(v != 0u))) break;
            __builtin_amdgcn_s_sleep(1);
        }
        int same = __all((int)(v == xcc + 1u));
        if (tid == 0) sh_lcl = same;
    }
    __syncthreads();
    const bool lcl = (sh_lcl != 0);

    float creg[2] = {0.f, 0.f};
    const int nn = tid & 31;
    const int aa = tid >> 5;            // 0..15: rows 2aa, 2aa+1

    unsigned* myflag = &flags[blockIdx.x * 32];
    // per-wave poll set: only the 8 producers of my k-quarter
    unsigned* pollflag = &flags[(((kq << 3) + (lane & 7)) * 8 + bt) * 32];

    for (int t = 0; t < T; ++t) {
        const float xv = x[(b0 + nn) * T + t];

        f32x16 acc0 = {0.f,0.f,0.f,0.f,0.f,0.f,0.f,0.f,
                       0.f,0.f,0.f,0.f,0.f,0.f,0.f,0.f};
        f32x16 acc1 = acc0;

        if (t > 0) {        // h_0 == 0 -> z == 0: skip poll+loads+MFMA at t=0
            // ---- per-wave wait on my 8 producers (IC protocol values) ----
            {
                const unsigned target = (unsigned)t;
                while (true) {
                    unsigned v = __hip_atomic_load(pollflag, __ATOMIC_RELAXED,
                                                   __HIP_MEMORY_SCOPE_AGENT);
                    if (__all((int)(v >= target))) break;
                    __builtin_amdgcn_s_sleep(1);
                }
            }
            // force xv retired so vmcnt counts below are exact
            __asm__ volatile("" :: "v"(xv));

            // ---- B-frags direct from global, counted-vmcnt MFMA ----
            const char* gb = frag + (t & 1) * 524288 + bt * 65536
                           + (kq << 14) + lane * 16;
            if (lcl) {       // XCD-local exchange: L2 hit (L1 bypass only)
                GATE_MFMA("sc0")
            } else {         // cross-XCD: IC path (round-11 semantics)
                GATE_MFMA("sc0 sc1")
            }
        }

        // C/D (HW-verified 32x32): col = lane&31,
        // row = (reg&3) + 8*(reg>>2) + 4*(lane>>5) = 4*grp + e, grp=2*rq+hi.
        // zb float idx: ((kq*4+g)<<10) + (col<<5) + ((grp^(col&7))<<2) + e.
        {
            float* zbF = &zb[0][0][0];
            const int col = lane & 31;
            const int hi  = lane >> 5;
            const int g0 = gp * 2, g1 = g0 + 1;
#pragma unroll
            for (int rq = 0; rq < 4; ++rq) {
                const int sw = ((2 * rq + hi) ^ (col & 7)) << 2;
                f32x4 w0, w1;
#pragma unroll
                for (int e = 0; e < 4; ++e) {
                    w0[e] = acc0[rq * 4 + e];
                    w1[e] = acc1[rq * 4 + e];
                }
                *(f32x4*)(zbF + ((kq * 4 + g0) << 10) + (col << 5) + sw) = w0;
                *(f32x4*)(zbF + ((kq * 4 + g1) << 10) + (col << 5) + sw) = w1;
            }
        }
        __syncthreads();   // all waves' polls done => all 32 peers >= t:
                           // stores below cannot overwrite a peer's live read

        // ---- elementwise epilogue: 512 threads x 2 rows (f32x2 zb reads) ----
        {
            const int grp = aa >> 1, half = aa & 1;  // rows 4grp+2half+{0,1}
            const float* zcol = &zb[0][0][0] + (nn << 5);
            const int fo = ((grp ^ (nn & 7)) << 2) + (half << 1);
            f32x2 zs[4];
#pragma unroll
            for (int gi = 0; gi < 4; ++gi) {
                f32x2 s = *(const f32x2*)(zcol + (gi << 10) + fo);
#pragma unroll
                for (int kk = 1; kk < 4; ++kk)
                    s += *(const f32x2*)(zcol + (((kk << 2) + gi) << 10) + fo);
                zs[gi] = s;
            }
            unsigned short hb[2];
#pragma unroll
            for (int q = 0; q < 2; ++q) {
                const int jl = 2 * aa + q;
                float zg = zs[0][q] + wxl[0][jl] * xv + bsl[0][nn];
                float zi = zs[1][q] + wxl[1][jl] * xv + bsl[1][nn];
                float zf = zs[2][q] + wxl[2][jl] * xv + bsl[2][nn];
                float zo = zs[3][q] + wxl[3][jl] * xv + bsl[3][nn];
                float g  = tanh_fast(zg);
                float ig = sigm_fast(zi);
                float fg = sigm_fast(zf);
                float og = sigm_fast(zo);
                creg[q] = g * ig + creg[q] * fg;
                float hn = tanh_fast(creg[q]) * og;
                hb[q] = bf16_bits(hn);
                if (t == T - 1) hfin[(j0 + jl) * B + (b0 + nn)] = hn;
            }
            // h store: rows j0+2aa, j0+2aa+1 -> one 4-B store (same octet).
            const unsigned val = (unsigned)hb[0] | ((unsigned)hb[1] << 16);
            const int jj = j0 + 2 * aa;
            short* fb = (short*)(frag + ((t + 1) & 1) * 524288) + bt * 32768;
            short* fdst = fb + (jj >> 4) * 512 + ((jj >> 3) & 1) * 256
                        + nn * 8 + (jj & 7);
            if (lcl) {
                // GENUINE write-back L2 store (no sc bits): stays dirty in
                // this XCD's L2; group peers (same XCD, det-proven) hit it
                // with their sc0 loads. This is the round-16 change.
                __asm__ volatile("global_store_dword %0, %1, off"
                                 :: "v"(fdst), "v"(val) : "memory");
            } else {
                __hip_atomic_store((unsigned*)fdst, val, __ATOMIC_RELAXED,
                                   __HIP_MEMORY_SCOPE_AGENT);
            }
        }

        // ---- arrive (round-11 IC protocol): barrier drains every wave's
        // store-acks (each wave waits vmcnt before s_barrier), then one flag --
        __syncthreads();
        if (tid == 0) {
            __asm__ volatile("s_waitcnt vmcnt(0)" ::: "memory");
            __hip_atomic_store(myflag, (unsigned)(t + 1), __ATOMIC_RELAXED,
                               __HIP_MEMORY_SCOPE_AGENT);
        }
    }
}

// ---------------- projection + softmax over batch --------------------------
__global__ __launch_bounds__(256) void lstm_final(
    const float* __restrict__ Wph, const float* __restrict__ hfin,
    const float* __restrict__ bp, float* __restrict__ out)
{
    __shared__ float sh[256];
    __shared__ float shm, shs;
    int c = blockIdx.x;
    int b = threadIdx.x;
    float acc = bp[b];
    const float* wr = Wph + c * H;
    for (int k = 0; k < H; ++k)
        acc += wr[k] * hfin[k * B + b];

    sh[b] = acc;
    __syncthreads();
    for (int s = 128; s > 0; s >>= 1) {
        if (b < s) sh[b] = fmaxf(sh[b], sh[b + s]);
        __syncthreads();
    }
    if (b == 0) shm = sh[0];
    __syncthreads();
    float e = expf(acc - shm);
    sh[b] = e;
    __syncthreads();
    for (int s = 128; s > 0; s >>= 1) {
        if (b < s) sh[b] += sh[b + s];
        __syncthreads();
    }
    if (b == 0) shs = sh[0];
    __syncthreads();
    out[b * NCLS + c] = e / shs;
}

extern "C" void kernel_launch(void* const* d_in, const int* in_sizes, int n_in,
                              void* d_out, int out_size, void* d_ws, size_t ws_size,
                              hipStream_t stream)
{
    const float* x   = (const float*)d_in[0];
    const float* Wgx = (const float*)d_in[1];
    const float* Wgh = (const float*)d_in[2];
    const float* Wix = (const float*)d_in[3];
    const float* Wih = (const float*)d_in[4];
    const float* Wfx = (const float*)d_in[5];
    const float* Wfh = (const float*)d_in[6];
    const float* Wox = (const float*)d_in[7];
    const float* Woh = (const float*)d_in[8];
    const float* Wph = (const float*)d_in[9];
    const float* bg  = (const float*)d_in[10];
    const float* bi  = (const float*)d_in[11];
    const float* bfv = (const float*)d_in[12];
    const float* bo  = (const float*)d_in[13];
    const float* bp  = (const float*)d_in[14];

    char* ws = (char*)d_ws;
    char* frag = ws;                                 // 1 MB (2 x 512 KB)
    unsigned* flags = (unsigned*)(ws + 1048576);     // 32 KB (256 x 128 B)
    unsigned* det   = (unsigned*)(ws + 1081344);     // 4 KB (256 x 4 B)
    float* hfin = (float*)(ws + 1085440);            // 1 MB

    // flags+det zeroed via IC-visible memset; frag needs no init (t=0 skip)
    hipMemsetAsync(flags, 0, 36864, stream);

    lstm_persist<<<256, 512, 0, stream>>>(
        x, Wgh, Wih, Wfh, Woh, Wgx, Wix, Wfx, Wox,
        bg, bi, bfv, bo, frag, flags, det, hfin);

    lstm_final<<<NCLS, 256, 0, stream>>>(Wph, hfin, bp, (float*)d_out);
}